// Round 1
// baseline (348.413 us; speedup 1.0000x reference)
//
#include <hip/hip_runtime.h>
#include <stdint.h>

#define DIN   4096
#define DOUT  4096
#define MTOT  8192
#define BM    128
#define BN    128
#define BK    64
#define NT    (DIN / BK)              /* 64 k-tiles */
#define GRID_N (DOUT / BN)            /* 32 */
#define NWG   ((MTOT / BM) * GRID_N)  /* 2048 */

typedef __attribute__((ext_vector_type(4))) float        f32x4;
typedef __attribute__((ext_vector_type(4))) int          i32x4;
typedef __attribute__((ext_vector_type(4))) unsigned int u32x4;
typedef __attribute__((ext_vector_type(2))) unsigned int u32x2;
typedef __attribute__((ext_vector_type(8))) short        bf16x8;

__device__ __forceinline__ unsigned int pack_bf2_rne(float a, float b) {
  unsigned int ua = __builtin_bit_cast(unsigned int, a);
  unsigned int ub = __builtin_bit_cast(unsigned int, b);
  ua += 0x7fffu + ((ua >> 16) & 1u);   // round-to-nearest-even
  ub += 0x7fffu + ((ub >> 16) & 1u);
  return (ua >> 16) | (ub & 0xffff0000u);
}

// (w - off) is an integer with |v| <= 135 < 256 -> exactly representable in bf16;
// truncation of the f32 bits is exact.
__device__ __forceinline__ unsigned int pack_bf2_exact(int a, int b) {
  unsigned int ua = __builtin_bit_cast(unsigned int, (float)a);
  unsigned int ub = __builtin_bit_cast(unsigned int, (float)b);
  return (ua >> 16) | (ub & 0xffff0000u);
}

// ---- pre-pass: x (fp32) -> bf16, tiled [rb][kt] 128x64, pre-swizzled ----
// within-tile byte layout: row*128 + ((chunk16*16) ^ ((row&7)<<4))
__global__ __launch_bounds__(256) void convA_kernel(const float* __restrict__ X,
                                                    u32x4* __restrict__ wsA) {
  const int total = MTOT * (DIN / 8);  // 16B chunks
  for (int idx = blockIdx.x * 256 + threadIdx.x; idx < total; idx += gridDim.x * 256) {
    const int m  = idx >> 9;          // /(DIN/8)
    const int c  = idx & 511;
    const int kt = c >> 3, ch = c & 7;
    const int rb = m >> 7, row = m & 127;
    const f32x4* src = (const f32x4*)(X + ((long)m << 12) + kt * 64 + ch * 8);
    f32x4 f0 = src[0], f1 = src[1];
    u32x4 d;
    d[0] = pack_bf2_rne(f0[0], f0[1]);
    d[1] = pack_bf2_rne(f0[2], f0[3]);
    d[2] = pack_bf2_rne(f1[0], f1[1]);
    d[3] = pack_bf2_rne(f1[2], f1[3]);
    wsA[(long)(rb * NT + kt) * 1024 + row * 8 + (ch ^ (row & 7))] = d;
  }
}

// ---- pre-pass: (w - offset) (int) -> bf16 exact, same tiling/swizzle ----
__global__ __launch_bounds__(256) void convB_kernel(const int* __restrict__ W,
                                                    const int* __restrict__ Off,
                                                    u32x4* __restrict__ wsB) {
  const int total = DOUT * (DIN / 8);
  for (int idx = blockIdx.x * 256 + threadIdx.x; idx < total; idx += gridDim.x * 256) {
    const int n  = idx >> 9;
    const int c  = idx & 511;
    const int kt = c >> 3, ch = c & 7;
    const int nb = n >> 7, row = n & 127;
    const i32x4* src = (const i32x4*)(W + ((long)n << 12) + kt * 64 + ch * 8);
    const int off = Off[n];
    i32x4 w0 = src[0], w1 = src[1];
    u32x4 d;
    d[0] = pack_bf2_exact(w0[0] - off, w0[1] - off);
    d[1] = pack_bf2_exact(w0[2] - off, w0[3] - off);
    d[2] = pack_bf2_exact(w1[0] - off, w1[1] - off);
    d[3] = pack_bf2_exact(w1[2] - off, w1[3] - off);
    wsB[(long)(nb * NT + kt) * 1024 + row * 8 + (ch ^ (row & 7))] = d;
  }
}

// ---- GEMM: 128x128 tile, BK=64, 4 waves (2x2 of 64x64), dbuf LDS ----
template <bool PRE>
__global__ __launch_bounds__(256, 2) void gemm_kernel(
    const u32x4* __restrict__ wsA, const u32x4* __restrict__ wsB,
    const float* __restrict__ X, const int* __restrict__ W,
    const int* __restrict__ Off, const float* __restrict__ Scale,
    float* __restrict__ Out) {
  __shared__ char ldsA[2][BM * BK * 2];
  __shared__ char ldsB[2][BN * BK * 2];

  const int tid  = threadIdx.x;
  const int lane = tid & 63;
  const int wid  = tid >> 6;
  const int wr   = wid >> 1;  // 0..1
  const int wc   = wid & 1;   // 0..1

  int gid = (int)blockIdx.x;
  gid = (gid & 7) * (NWG >> 3) + (gid >> 3);  // bijective XCD swizzle (2048%8==0)
  const int wg_m = gid / GRID_N;
  const int wg_n = gid % GRID_N;
  const int brow = wg_m * BM;
  const int bcol = wg_n * BN;

  f32x4 acc[4][4];
#pragma unroll
  for (int m = 0; m < 4; ++m)
#pragma unroll
    for (int n = 0; n < 4; ++n) acc[m][n] = (f32x4){0.f, 0.f, 0.f, 0.f};

  // fragment LDS byte offsets (swizzled), compile-time-indexed only
  int aoff[2][4], boff[2][4];
#pragma unroll
  for (int kk = 0; kk < 2; ++kk)
#pragma unroll
    for (int m = 0; m < 4; ++m) {
      const int kb = kk * 64 + ((lane >> 4) << 4);
      const int ra = wr * 64 + m * 16 + (lane & 15);
      const int rb = wc * 64 + m * 16 + (lane & 15);
      aoff[kk][m] = ra * 128 + (kb ^ ((ra & 7) << 4));
      boff[kk][m] = rb * 128 + (kb ^ ((rb & 7) << 4));
    }

  auto compute = [&](int buf) {
#pragma unroll
    for (int kk = 0; kk < 2; ++kk) {
      bf16x8 a[4], b[4];
#pragma unroll
      for (int m = 0; m < 4; ++m)
        a[m] = __builtin_bit_cast(bf16x8, *(const u32x4*)(&ldsA[buf][aoff[kk][m]]));
#pragma unroll
      for (int n = 0; n < 4; ++n)
        b[n] = __builtin_bit_cast(bf16x8, *(const u32x4*)(&ldsB[buf][boff[kk][n]]));
#pragma unroll
      for (int m = 0; m < 4; ++m)
#pragma unroll
        for (int n = 0; n < 4; ++n)
          acc[m][n] = __builtin_amdgcn_mfma_f32_16x16x32_bf16(a[m], b[n], acc[m][n], 0, 0, 0);
    }
  };

  if constexpr (PRE) {
    const u32x4* tA = wsA + (long)wg_m * NT * 1024;
    const u32x4* tB = wsB + (long)wg_n * NT * 1024;

    auto stage = [&](int kt, int buf) {
      const u32x4* sa = tA + (long)kt * 1024;
      const u32x4* sb = tB + (long)kt * 1024;
#pragma unroll
      for (int i = 0; i < 4; ++i) {
        const int o = tid + i * 256;
        __builtin_amdgcn_global_load_lds(
            (const __attribute__((address_space(1))) void*)(sa + o),
            (__attribute__((address_space(3))) void*)(&ldsA[buf][o * 16]), 16, 0, 0);
        __builtin_amdgcn_global_load_lds(
            (const __attribute__((address_space(1))) void*)(sb + o),
            (__attribute__((address_space(3))) void*)(&ldsB[buf][o * 16]), 16, 0, 0);
      }
    };

    stage(0, 0);
    __syncthreads();
#pragma unroll 1
    for (int kt = 0; kt < NT; ++kt) {
      const int cur = kt & 1;
      if (kt + 1 < NT) stage(kt + 1, cur ^ 1);
      compute(cur);
      __syncthreads();
    }
  } else {
    // fused fallback: reg-stage with on-the-fly conversion
    long xo[8], wo[8];
    int lo[8], ofv[8];
#pragma unroll
    for (int i = 0; i < 8; ++i) {
      const int idx = tid + i * 256;
      const int row = idx >> 4, c4 = idx & 15;
      xo[i] = (long)(brow + row) * DIN + c4 * 4;
      wo[i] = (long)(bcol + row) * DIN + c4 * 4;
      lo[i] = row * 128 + ((c4 * 8) ^ ((row & 7) << 4));
      ofv[i] = Off[bcol + row];
    }
    {
#pragma unroll
      for (int i = 0; i < 8; ++i) {
        f32x4 f = *(const f32x4*)(X + xo[i]);
        u32x2 d;
        d[0] = pack_bf2_rne(f[0], f[1]);
        d[1] = pack_bf2_rne(f[2], f[3]);
        *(u32x2*)(&ldsA[0][lo[i]]) = d;
      }
#pragma unroll
      for (int i = 0; i < 8; ++i) {
        i32x4 w = *(const i32x4*)(W + wo[i]);
        u32x2 d;
        d[0] = pack_bf2_exact(w[0] - ofv[i], w[1] - ofv[i]);
        d[1] = pack_bf2_exact(w[2] - ofv[i], w[3] - ofv[i]);
        *(u32x2*)(&ldsB[0][lo[i]]) = d;
      }
    }
    __syncthreads();
#pragma unroll 1
    for (int kt = 0; kt < NT; ++kt) {
      const int cur = kt & 1;
      const bool pf = (kt + 1 < NT);
      f32x4 fa[8];
      i32x4 fb[8];
      if (pf) {
        const int ko = (kt + 1) * BK;
#pragma unroll
        for (int i = 0; i < 8; ++i) fa[i] = *(const f32x4*)(X + xo[i] + ko);
#pragma unroll
        for (int i = 0; i < 8; ++i) fb[i] = *(const i32x4*)(W + wo[i] + ko);
      }
      compute(cur);
      if (pf) {
        char* dA = ldsA[cur ^ 1];
        char* dB = ldsB[cur ^ 1];
#pragma unroll
        for (int i = 0; i < 8; ++i) {
          u32x2 d;
          d[0] = pack_bf2_rne(fa[i][0], fa[i][1]);
          d[1] = pack_bf2_rne(fa[i][2], fa[i][3]);
          *(u32x2*)(&dA[lo[i]]) = d;
        }
#pragma unroll
        for (int i = 0; i < 8; ++i) {
          u32x2 d;
          d[0] = pack_bf2_exact(fb[i][0] - ofv[i], fb[i][1] - ofv[i]);
          d[1] = pack_bf2_exact(fb[i][2] - ofv[i], fb[i][3] - ofv[i]);
          *(u32x2*)(&dB[lo[i]]) = d;
        }
      }
      __syncthreads();
    }
  }

  // epilogue: out = acc * scale[col]   (C/D map: col=lane&15, row=(lane>>4)*4+j)
  const int col0 = bcol + wc * 64 + (lane & 15);
  const int row0 = brow + wr * 64 + ((lane >> 4) << 2);
#pragma unroll
  for (int n = 0; n < 4; ++n) {
    const int col = col0 + n * 16;
    const float s = Scale[col];
#pragma unroll
    for (int m = 0; m < 4; ++m) {
      const int r = row0 + m * 16;
#pragma unroll
      for (int j = 0; j < 4; ++j)
        Out[(long)(r + j) * DOUT + col] = acc[m][n][j] * s;
    }
  }
}

extern "C" void kernel_launch(void* const* d_in, const int* in_sizes, int n_in,
                              void* d_out, int out_size, void* d_ws, size_t ws_size,
                              hipStream_t stream) {
  (void)in_sizes; (void)n_in; (void)out_size;
  const float* X  = (const float*)d_in[0];
  const int*   W  = (const int*)d_in[1];
  const float* Sc = (const float*)d_in[2];
  const int*   Of = (const int*)d_in[3];
  float* Out = (float*)d_out;

  const size_t needA = (size_t)MTOT * DIN * 2;  // 64 MiB bf16 x
  const size_t needB = (size_t)DOUT * DIN * 2;  // 32 MiB bf16 w
  if (ws_size >= needA + needB) {
    u32x4* wsA = (u32x4*)d_ws;
    u32x4* wsB = (u32x4*)((char*)d_ws + needA);
    convA_kernel<<<2048, 256, 0, stream>>>(X, wsA);
    convB_kernel<<<2048, 256, 0, stream>>>(W, Of, wsB);
    gemm_kernel<true><<<NWG, 256, 0, stream>>>(wsA, wsB, X, W, Of, Sc, Out);
  } else {
    gemm_kernel<false><<<NWG, 256, 0, stream>>>(nullptr, nullptr, X, W, Of, Sc, Out);
  }
}